// Round 18
// baseline (1983.995 us; speedup 1.0000x reference)
//
#include <hip/hip_runtime.h>
#include <stdint.h>

#define BB    4096   // batch
#define Z1D   128
#define CD    12     // cond dim
#define HD    1024   // hidden
#define TT    32     // steps
#define N3H   3072   // 3*HD
#define KAUG  1216   // 1024 h + 12 feed + 128 z + 52 pad = 19*64
#define NGP   3264   // Wg rows: 3072 gates + 12 Wout + pad (17*192)
#define NPH0B 1088   // padded rows for prologue B matrices
#define ACOLS 192    // A-state cols re-inited by prep (1024..1216)
#define KS64  19     // K-steps (BK=64) in main GEMM

typedef __bf16 bf16;
typedef __bf16 bf16x2 __attribute__((ext_vector_type(2)));
typedef __bf16 bf16x8 __attribute__((ext_vector_type(8)));
typedef float  f32x4  __attribute__((ext_vector_type(4)));
typedef float  f4     __attribute__((ext_vector_type(4)));

typedef const __attribute__((address_space(1))) void* as1cv;
typedef __attribute__((address_space(3))) void* as3v;

__device__ __forceinline__ float sigm(float x){ return 1.0f/(1.0f+__expf(-x)); }
__device__ __forceinline__ float tanhfast(float x){ return 1.0f - 2.0f/(1.0f+__expf(2.0f*x)); }

// interleaved column index n' -> original gate row (g*1024 + jn)
// 96-wide groups: [r(32) | z(32) | n_h(32)] for 32 consecutive hidden cols
__device__ __forceinline__ int rowOfN(int np, int& g){
  int jb = np/96; int r = np - jb*96; g = r>>5; int jl = r&31;
  return g*1024 + jb*32 + jl;
}

// ---------------- prep: weight conversion / layout / state init ----------------
__global__ __launch_bounds__(256)
void prep_k(const float* __restrict__ z, const float* __restrict__ Wih,
            const float* __restrict__ Whh, const float* __restrict__ bih,
            const float* __restrict__ bhh, const float* __restrict__ Winit,
            const float* __restrict__ Wout,
            bf16* __restrict__ Wg, bf16* __restrict__ Wzn, bf16* __restrict__ Wi0,
            bf16* __restrict__ zbf, float* __restrict__ biasz,
            float* __restrict__ bhhn, float* __restrict__ bihn,
            bf16* __restrict__ A0, bf16* __restrict__ A1)
{
  const int N1 = NGP*KAUG;       // Wg: gates interleaved + Wout rows + pad
  const int N2 = NPH0B*Z1D;      // Wzn
  const int N3 = NPH0B*Z1D;      // Wi0
  const int N4 = BB*Z1D;         // zbf
  const int N5 = N3H;            // biasz (r,z: bih+bhh)
  const int N6 = HD;             // bhhn
  const int N6b= HD;             // bihn
  const int N7 = 2*BB*ACOLS;     // A0/A1 init: cols 1024..1216 only
  int idx = blockIdx.x*256 + threadIdx.x;
  if (idx < N1){
    int np = idx/KAUG, k = idx - np*KAUG;
    float v = 0.0f;
    if (np < N3H){
      int g; int row = rowOfN(np, g);
      if (k < 1024) v = Whh[(size_t)row*HD + k];
      else if (g < 2){
        if (k < 1036)      v = Wih[(size_t)row*140 + (k-1024)];       // feed cols
        else if (k < 1164) v = Wih[(size_t)row*140 + 12 + (k-1036)];  // z cols
      }
    } else {
      int c = np - N3H;                  // out-projection rows (3072..3083)
      if (c < CD && k < 1024) v = Wout[(size_t)c*HD + k];
    }
    Wg[idx] = (bf16)v;
    return;
  }
  idx -= N1;
  if (idx < N2){
    int jn = idx/Z1D, kk = idx - jn*Z1D;
    Wzn[idx] = (jn < HD) ? (bf16)Wih[(size_t)(2048+jn)*140 + 12 + kk] : (bf16)0.0f;
    return;
  }
  idx -= N2;
  if (idx < N3){
    int jn = idx/Z1D, kk = idx - jn*Z1D;
    Wi0[idx] = (jn < HD) ? (bf16)Winit[(size_t)jn*Z1D + kk] : (bf16)0.0f;
    return;
  }
  idx -= N3;
  if (idx < N4){ zbf[idx] = (bf16)z[idx]; return; }
  idx -= N4;
  if (idx < N5){
    int g; int row = rowOfN(idx, g);
    biasz[idx] = (g < 2) ? (bih[row] + bhh[row]) : 0.0f;
    return;
  }
  idx -= N5;
  if (idx < N6){ bhhn[idx] = bhh[2048 + idx]; return; }
  idx -= N6;
  if (idx < N6b){ bihn[idx] = bih[2048 + idx]; return; }
  idx -= N6b;
  if (idx < N7){
    int j = (idx < BB*ACOLS) ? idx : idx - BB*ACOLS;
    int b = j / ACOLS, kk = j - b*ACOLS;
    int k = 1024 + kk;                   // feed(12) | z(128) | pad(52)
    bf16 v = (bf16)0.0f;
    if (k >= 1036 && k < 1164) v = (bf16)z[(size_t)b*Z1D + (k-1036)];
    if (idx < BB*ACOLS) A0[(size_t)b*KAUG + k] = v;
    else                A1[(size_t)b*KAUG + k] = v;
  }
}

// ---------------- prologue GEMM (zpn / h0), proven R9 structure, BK=32 ----------------
template<int EP>
__global__ __launch_bounds__(256, 5)
void gemm_k(const bf16* __restrict__ A, int lda,
            const bf16* __restrict__ Bw, int ldb, int ksteps,
            bf16* __restrict__ zpnw, const float* __restrict__ bias1,
            bf16* __restrict__ Anext)
{
  __shared__ bf16 lA[2][128*32];
  __shared__ bf16 lB[2][96*32];
  const int tid = threadIdx.x, wid = tid>>6, lane = tid&63;
  const int l15 = lane&15, l4 = lane>>4;
  const int bx = blockIdx.x, by = blockIdx.y;
  const int n0 = bx*96, m0 = by*128;

  f32x4 acc[2][6];
  #pragma unroll
  for (int i=0;i<2;++i)
    #pragma unroll
    for (int j=0;j<6;++j) acc[i][j] = (f32x4){0.f,0.f,0.f,0.f};

  auto STAGE = [&](int buf, int ks){
    const int k0 = ks*32;
    const bf16* gA = A + (size_t)m0*lda + k0;
    #pragma unroll
    for (int r=0; r<2; ++r){
      int q = r*256 + tid;
      int row = q>>2, slot = q&3;
      int sg = slot ^ ((row>>1)&3);
      const bf16* gp = gA + (size_t)row*lda + sg*8;
      bf16* lp = &lA[buf][(size_t)(r*256 + wid*64)*8];
      __builtin_amdgcn_global_load_lds((as1cv)gp, (as3v)lp, 16, 0, 0);
    }
    const bf16* gB = Bw + (size_t)n0*ldb + k0;
    {
      int q = tid;
      int row = q>>2, slot = q&3;
      int sg = slot ^ ((row>>1)&3);
      const bf16* gp = gB + (size_t)row*ldb + sg*8;
      bf16* lp = &lB[buf][(size_t)(wid*64)*8];
      __builtin_amdgcn_global_load_lds((as1cv)gp, (as3v)lp, 16, 0, 0);
    }
    if (tid < 128){
      int q = 256 + tid;
      int row = q>>2, slot = q&3;
      int sg = slot ^ ((row>>1)&3);
      const bf16* gp = gB + (size_t)row*ldb + sg*8;
      bf16* lp = &lB[buf][(size_t)(256 + wid*64)*8];
      __builtin_amdgcn_global_load_lds((as1cv)gp, (as3v)lp, 16, 0, 0);
    }
  };

  const int sl = (l4 ^ ((l15>>1)&3))*8;
  int cur = 0;
  STAGE(0, 0);
  for (int ks=0; ks<ksteps; ++ks){
    __syncthreads();
    if (ks+1 < ksteps) STAGE(cur^1, ks+1);
    bf16x8 af0 = *(const bf16x8*)&lA[cur][(wid*32 +  0 + l15)*32 + sl];
    bf16x8 af1 = *(const bf16x8*)&lA[cur][(wid*32 + 16 + l15)*32 + sl];
    #pragma unroll
    for (int cf=0; cf<6; ++cf){
      bf16x8 bfr = *(const bf16x8*)&lB[cur][(cf*16 + l15)*32 + sl];
      acc[0][cf] = __builtin_amdgcn_mfma_f32_16x16x32_bf16(af0, bfr, acc[0][cf], 0,0,0);
      acc[1][cf] = __builtin_amdgcn_mfma_f32_16x16x32_bf16(af1, bfr, acc[1][cf], 0,0,0);
    }
    cur ^= 1;
  }

  const int rbase = m0 + wid*32 + l4*4;
  #pragma unroll
  for (int rf=0; rf<2; ++rf)
    #pragma unroll
    for (int cf=0; cf<6; ++cf){
      int jn = n0 + cf*16 + l15;
      if (jn < HD){
        float bi = bias1[jn];
        #pragma unroll
        for (int reg=0; reg<4; ++reg){
          int b = rbase + rf*16 + reg;
          if constexpr (EP == 0)
            zpnw[(size_t)b*HD + jn] = (bf16)(acc[rf][cf][reg] + bi);
          else
            Anext[(size_t)b*KAUG + jn] = (bf16)tanhfast(acc[rf][cf][reg] + bi);
        }
      }
    }
}

// ---------------- main step GEMM: tile 128x192, BK=64, 4 waves (2M x 2N) ----------------
// Counted-vmcnt pipeline (T4): STAGE(k+1) -> s_waitcnt vmcnt(10) (waits only
// buffer-k's 10/thread loads, issued one full iteration earlier) -> s_barrier
// -> 48 MFMA -> memfence + s_barrier (WAR). Never drains vmcnt in-loop.
// XCD-pinned transposed map: XCD x owns bx in {2x,2x+1} (Wg slice 0.93 MB ->
// L2-resident) x all by, + 4 out-tile blocks. XOR swizzle slot^=(row&7).
__global__ __launch_bounds__(256, 2)
void gru_step(const bf16* __restrict__ Acur, const bf16* __restrict__ Wg,
              const bf16* __restrict__ zpn, const float* __restrict__ biasz,
              const float* __restrict__ bhhn, const float* __restrict__ Wih,
              const float* __restrict__ cond, bf16* __restrict__ Anext,
              const float* __restrict__ bout, float* __restrict__ outg, int t)
{
  __shared__ bf16 lA[2][128*64];
  __shared__ bf16 lB[2][192*64];
  const int tid = threadIdx.x, wid = tid>>6, lane = tid&63;
  const int l15 = lane&15, l4 = lane>>4;
  const int wm = wid>>1, wn = wid&1;

  // XCD x (bid&7) owns bx {2x,2x+1} x by 0..31, plus out-tile by {4x..4x+3}
  const int bid = blockIdx.x;
  const int x = bid & 7, k = bid >> 3;   // k 0..67
  int bx, by;
  if (k < 64){ bx = x*2 + (k>>5); by = k & 31; }
  else       { bx = 16;           by = x*4 + (k-64); }
  const int n0 = bx*192, m0 = by*128;

  f32x4 acc[4][6];
  #pragma unroll
  for (int i=0;i<4;++i)
    #pragma unroll
    for (int j=0;j<6;++j) acc[i][j] = (f32x4){0.f,0.f,0.f,0.f};

  // stage K-tile (64 cols): uniform 10 loads/thread (4 A + 6 B, 16B each).
  // LDS dest linear; global source 16B-slot XOR-swizzled: sg = slot ^ (row&7).
  auto STAGE = [&](int buf, int ks){
    const int k0 = ks*64;
    const bf16* gA = Acur + (size_t)m0*KAUG + k0;
    #pragma unroll
    for (int r=0; r<4; ++r){
      int q = r*256 + tid;
      int row = q>>3, slot = q&7;
      int sg = slot ^ (row&7);
      const bf16* gp = gA + (size_t)row*KAUG + sg*8;
      bf16* lp = &lA[buf][(size_t)(r*256 + wid*64)*8];
      __builtin_amdgcn_global_load_lds((as1cv)gp, (as3v)lp, 16, 0, 0);
    }
    const bf16* gB = Wg + (size_t)n0*KAUG + k0;
    #pragma unroll
    for (int r=0; r<6; ++r){
      int q = r*256 + tid;
      int row = q>>3, slot = q&7;
      int sg = slot ^ (row&7);
      const bf16* gp = gB + (size_t)row*KAUG + sg*8;
      bf16* lp = &lB[buf][(size_t)(r*256 + wid*64)*8];
      __builtin_amdgcn_global_load_lds((as1cv)gp, (as3v)lp, 16, 0, 0);
    }
  };

  int cur = 0;
  STAGE(0, 0);
  for (int ks=0; ks<KS64; ++ks){
    if (ks+1 < KS64){
      STAGE(cur^1, ks+1);                // 20 outstanding/thread
      asm volatile("s_waitcnt vmcnt(10)" ::: "memory");   // wait cur's 10 only
    } else {
      asm volatile("s_waitcnt vmcnt(0)" ::: "memory");
    }
    __builtin_amdgcn_s_barrier();        // buf[cur] ready on all waves
    #pragma unroll
    for (int kk=0; kk<2; ++kk){
      bf16x8 af[4];
      #pragma unroll
      for (int mf=0; mf<4; ++mf){
        int row = wm*64 + mf*16 + l15;
        int sp = (kk*4 + l4) ^ (row&7);
        af[mf] = *(const bf16x8*)&lA[cur][row*64 + sp*8];
      }
      #pragma unroll
      for (int nf=0; nf<6; ++nf){
        int row = wn*96 + nf*16 + l15;
        int sp = (kk*4 + l4) ^ (row&7);
        bf16x8 bfr = *(const bf16x8*)&lB[cur][row*64 + sp*8];
        acc[0][nf] = __builtin_amdgcn_mfma_f32_16x16x32_bf16(af[0], bfr, acc[0][nf], 0,0,0);
        acc[1][nf] = __builtin_amdgcn_mfma_f32_16x16x32_bf16(af[1], bfr, acc[1][nf], 0,0,0);
        acc[2][nf] = __builtin_amdgcn_mfma_f32_16x16x32_bf16(af[2], bfr, acc[2][nf], 0,0,0);
        acc[3][nf] = __builtin_amdgcn_mfma_f32_16x16x32_bf16(af[3], bfr, acc[3][nf], 0,0,0);
      }
    }
    asm volatile("" ::: "memory");       // keep ds_reads before the WAR barrier
    __builtin_amdgcn_s_barrier();        // all reads of buf[cur] done
    cur ^= 1;
  }

  const int rbase = m0 + wm*64 + l4*4;   // + mf*16 + reg

  if (bx == 16){
    // out-projection tile: wn==0 waves cover cols 3072..3167 (Wout rows at 3072)
    if (wn == 0 && t > 0 && l15 < CD){
      float bo = bout[l15];
      #pragma unroll
      for (int mf=0; mf<4; ++mf){
        #pragma unroll
        for (int reg=0; reg<4; ++reg){
          int b = rbase + mf*16 + reg;
          outg[((size_t)b*TT + (t-1))*CD + l15] = sigm(acc[mf][0][reg] + bo);
        }
      }
    }
  } else {
    const int jg = bx*2 + wn;            // gate group 0..31
    // n-gate feed weights: W_ih[2048+jn, 0:12]
    float wfn[2][12];
    #pragma unroll
    for (int jf=0; jf<2; ++jf){
      int jn = jg*32 + jf*16 + l15;
      const f4* wr = (const f4*)(Wih + (size_t)(2048 + jn)*140);
      f4 w0 = wr[0], w1 = wr[1], w2 = wr[2];
      #pragma unroll
      for (int c=0;c<4;++c){ wfn[jf][c]=w0[c]; wfn[jf][4+c]=w1[c]; wfn[jf][8+c]=w2[c]; }
    }
    #pragma unroll
    for (int mf=0; mf<4; ++mf){
      #pragma unroll
      for (int reg=0; reg<4; ++reg){
        int b = rbase + mf*16 + reg;
        const bf16* fr = Acur + (size_t)b*KAUG + 1024;
        bf16x8 f8 = *(const bf16x8*)fr;
        float fd[12];
        #pragma unroll
        for (int c=0;c<8;++c) fd[c] = (float)f8[c];
        #pragma unroll
        for (int c=8;c<12;++c) fd[c] = (float)fr[c];
        #pragma unroll
        for (int jf=0; jf<2; ++jf){
          int jn = jg*32 + jf*16 + l15;
          int np = jg*96 + jf*16 + l15;
          float aR = acc[mf][jf  ][reg] + biasz[np];
          float aZ = acc[mf][2+jf][reg] + biasz[np+32];
          float hN = acc[mf][4+jf][reg] + bhhn[jn];
          float iN = (float)zpn[(size_t)b*HD + jn];
          float fdot = 0.0f;
          #pragma unroll
          for (int c=0;c<12;++c) fdot += fd[c]*wfn[jf][c];
          float r = sigm(aR);
          float u = sigm(aZ);
          float nn = tanhfast(iN + fdot + r*hN);
          float hp = (float)Acur[(size_t)b*KAUG + jn];
          float hv = (1.0f-u)*nn + u*hp;
          Anext[(size_t)b*KAUG + jn] = (bf16)hv;
        }
      }
    }
    // feed columns of A_next for step t+1 : condition[:, t, :]
    if (bx == 0 && wn == 0){
      // one wave-pair per by handles the 12 feed cols (wn==0 suffices; use all 256? keep tid-strided)
    }
    if (bx == 0){
      for (int i = tid; i < 128*CD; i += 256){
        int rr = i/CD, c = i - rr*CD;
        int b = m0 + rr;
        Anext[(size_t)b*KAUG + 1024 + c] = (bf16)cond[((size_t)b*TT + t)*CD + c];
      }
    }
  }
}

// ---------------- final-step output projection ----------------
__global__ __launch_bounds__(256)
void out_k(const bf16* __restrict__ hstate, const float* __restrict__ Wout,
           const float* __restrict__ bout, float* __restrict__ out, int t)
{
  __shared__ float sw[CD*HD];
  __shared__ float sb[CD];
  const int tid = threadIdx.x;
  for (int i=tid; i<CD*HD; i+=256) sw[i] = Wout[i];
  if (tid < CD) sb[tid] = bout[tid];
  __syncthreads();
  const int wid = tid>>6, lane = tid&63;
  const int b0 = blockIdx.x*8 + wid*2;
  for (int rr=0; rr<2; ++rr){
    int b = b0 + rr;
    const bf16* hr = hstate + (size_t)b*KAUG;
    float p[CD];
    #pragma unroll
    for (int c=0;c<CD;++c) p[c] = 0.0f;
    #pragma unroll
    for (int j=0;j<8;++j){
      int idx = lane*2 + j*128;
      bf16x2 hv = *(const bf16x2*)&hr[idx];
      float h0 = (float)hv[0], h1 = (float)hv[1];
      #pragma unroll
      for (int c=0;c<CD;++c) p[c] += h0*sw[c*HD + idx] + h1*sw[c*HD + idx + 1];
    }
    #pragma unroll
    for (int c=0;c<CD;++c){
      float v = p[c];
      #pragma unroll
      for (int m=32;m>=1;m>>=1) v += __shfl_xor(v, m, 64);
      if (lane == 0) out[((size_t)b*TT + t)*CD + c] = sigm(v + sb[c]);
    }
  }
}

// ---------------- launch ----------------
extern "C" void kernel_launch(void* const* d_in, const int* in_sizes, int n_in,
                              void* d_out, int out_size, void* d_ws, size_t ws_size,
                              hipStream_t stream) {
  const float* z     = (const float*)d_in[0];
  const float* cond  = (const float*)d_in[1];
  const float* Wih   = (const float*)d_in[3];
  const float* Whh   = (const float*)d_in[4];
  const float* bih   = (const float*)d_in[5];
  const float* bhh   = (const float*)d_in[6];
  const float* Winit = (const float*)d_in[7];
  const float* binit = (const float*)d_in[8];
  const float* Wout  = (const float*)d_in[9];
  const float* bout  = (const float*)d_in[10];
  float* out = (float*)d_out;

  char* ws = (char*)d_ws;
  size_t off = 0;
  auto carve = [&](size_t bytes)->char*{
    char* p = ws + off; off += (bytes + 255) & ~(size_t)255; return p;
  };
  bf16*  Wg    = (bf16*) carve((size_t)NGP*KAUG*2);
  bf16*  Wzn   = (bf16*) carve((size_t)NPH0B*Z1D*2);
  bf16*  Wi0   = (bf16*) carve((size_t)NPH0B*Z1D*2);
  bf16*  zbf   = (bf16*) carve((size_t)BB*Z1D*2);
  float* biasz = (float*)carve((size_t)N3H*4);
  float* bhhn  = (float*)carve((size_t)HD*4);
  float* bihn  = (float*)carve((size_t)HD*4);
  bf16*  zpn   = (bf16*) carve((size_t)BB*HD*2);
  bf16*  A0    = (bf16*) carve((size_t)BB*KAUG*2);
  bf16*  A1    = (bf16*) carve((size_t)BB*KAUG*2);

  // prep
  {
    long total = (long)NGP*KAUG + 2L*NPH0B*Z1D + (long)BB*Z1D + N3H + 2*HD
               + 2L*BB*ACOLS;
    int blocks = (int)((total + 255)/256);
    prep_k<<<blocks, 256, 0, stream>>>(z, Wih, Whh, bih, bhh, Winit, Wout,
                                       Wg, Wzn, Wi0, zbf, biasz, bhhn, bihn,
                                       A0, A1);
  }
  // zpn : n-gate z-projection + bih_n -> bf16. M=4096, N=1024(pad), K=128
  gemm_k<0><<<dim3(11,32), 256, 0, stream>>>(zbf, Z1D, Wzn, Z1D, 4,
      zpn, bihn, nullptr);
  // h0 : tanh(z@Winit^T + binit) -> A0 state cols. M=4096, N=1024(pad), K=128
  gemm_k<1><<<dim3(11,32), 256, 0, stream>>>(zbf, Z1D, Wi0, Z1D, 4,
      nullptr, binit, A0);

  for (int t = 0; t < TT; ++t){
    const bf16* Ac = (t & 1) ? A1 : A0;
    bf16*       An = (t & 1) ? A0 : A1;
    gru_step<<<544, 256, 0, stream>>>(Ac, Wg, zpn, biasz, bhhn, Wih, cond,
                                      An, bout, out, t);
  }
  // final step t=31: state is in A0 (t=31 odd -> An=A0)
  out_k<<<512, 256, 0, stream>>>(A0, Wout, bout, out, 31);
}

// Round 19
// 1849.781 us; speedup vs baseline: 1.0726x; 1.0726x over previous
//
#include <hip/hip_runtime.h>
#include <stdint.h>

#define BB    4096   // batch
#define Z1D   128
#define CD    12     // cond dim
#define HD    1024   // hidden
#define TT    32     // steps
#define N3H   3072   // 3*HD
#define KAUG  1216   // 1024 h + 12 feed + 128 z + 52 pad = 19*64
#define NGP   3264   // Wg rows: 3072 gates + 12 Wout + pad (17*192)
#define NPH0B 1088   // padded rows for prologue B matrices
#define ACOLS 192    // A-state cols re-inited by prep (1024..1216)
#define KS64  19     // K-steps (BK=64) in main GEMM

typedef __bf16 bf16;
typedef __bf16 bf16x2 __attribute__((ext_vector_type(2)));
typedef __bf16 bf16x8 __attribute__((ext_vector_type(8)));
typedef float  f32x4  __attribute__((ext_vector_type(4)));
typedef float  f4     __attribute__((ext_vector_type(4)));

typedef const __attribute__((address_space(1))) void* as1cv;
typedef __attribute__((address_space(3))) void* as3v;

__device__ __forceinline__ float sigm(float x){ return 1.0f/(1.0f+__expf(-x)); }
__device__ __forceinline__ float tanhfast(float x){ return 1.0f - 2.0f/(1.0f+__expf(2.0f*x)); }

// interleaved column index n' -> original gate row (g*1024 + jn)
// 96-wide groups: [r(32) | z(32) | n_h(32)] for 32 consecutive hidden cols
__device__ __forceinline__ int rowOfN(int np, int& g){
  int jb = np/96; int r = np - jb*96; g = r>>5; int jl = r&31;
  return g*1024 + jb*32 + jl;
}

// ---------------- prep: weight conversion / layout / state init ----------------
__global__ __launch_bounds__(256)
void prep_k(const float* __restrict__ z, const float* __restrict__ Wih,
            const float* __restrict__ Whh, const float* __restrict__ bih,
            const float* __restrict__ bhh, const float* __restrict__ Winit,
            const float* __restrict__ Wout,
            bf16* __restrict__ Wg, bf16* __restrict__ Wzn, bf16* __restrict__ Wi0,
            bf16* __restrict__ zbf, float* __restrict__ biasz,
            float* __restrict__ bhhn, float* __restrict__ bihn,
            bf16* __restrict__ A0, bf16* __restrict__ A1)
{
  const int N1 = NGP*KAUG;       // Wg: gates interleaved + Wout rows + pad
  const int N2 = NPH0B*Z1D;      // Wzn
  const int N3 = NPH0B*Z1D;      // Wi0
  const int N4 = BB*Z1D;         // zbf
  const int N5 = N3H;            // biasz (r,z: bih+bhh)
  const int N6 = HD;             // bhhn
  const int N6b= HD;             // bihn
  const int N7 = 2*BB*ACOLS;     // A0/A1 init: cols 1024..1216 only
  int idx = blockIdx.x*256 + threadIdx.x;
  if (idx < N1){
    int np = idx/KAUG, k = idx - np*KAUG;
    float v = 0.0f;
    if (np < N3H){
      int g; int row = rowOfN(np, g);
      if (k < 1024) v = Whh[(size_t)row*HD + k];
      else if (g < 2){
        if (k < 1036)      v = Wih[(size_t)row*140 + (k-1024)];       // feed cols
        else if (k < 1164) v = Wih[(size_t)row*140 + 12 + (k-1036)];  // z cols
      }
    } else {
      int c = np - N3H;                  // out-projection rows (3072..3083)
      if (c < CD && k < 1024) v = Wout[(size_t)c*HD + k];
    }
    Wg[idx] = (bf16)v;
    return;
  }
  idx -= N1;
  if (idx < N2){
    int jn = idx/Z1D, kk = idx - jn*Z1D;
    Wzn[idx] = (jn < HD) ? (bf16)Wih[(size_t)(2048+jn)*140 + 12 + kk] : (bf16)0.0f;
    return;
  }
  idx -= N2;
  if (idx < N3){
    int jn = idx/Z1D, kk = idx - jn*Z1D;
    Wi0[idx] = (jn < HD) ? (bf16)Winit[(size_t)jn*Z1D + kk] : (bf16)0.0f;
    return;
  }
  idx -= N3;
  if (idx < N4){ zbf[idx] = (bf16)z[idx]; return; }
  idx -= N4;
  if (idx < N5){
    int g; int row = rowOfN(idx, g);
    biasz[idx] = (g < 2) ? (bih[row] + bhh[row]) : 0.0f;
    return;
  }
  idx -= N5;
  if (idx < N6){ bhhn[idx] = bhh[2048 + idx]; return; }
  idx -= N6;
  if (idx < N6b){ bihn[idx] = bih[2048 + idx]; return; }
  idx -= N6b;
  if (idx < N7){
    int j = (idx < BB*ACOLS) ? idx : idx - BB*ACOLS;
    int b = j / ACOLS, kk = j - b*ACOLS;
    int k = 1024 + kk;                   // feed(12) | z(128) | pad(52)
    bf16 v = (bf16)0.0f;
    if (k >= 1036 && k < 1164) v = (bf16)z[(size_t)b*Z1D + (k-1036)];
    if (idx < BB*ACOLS) A0[(size_t)b*KAUG + k] = v;
    else                A1[(size_t)b*KAUG + k] = v;
  }
}

// ---------------- prologue GEMM (zpn / h0), proven R9 structure, BK=32 ----------------
template<int EP>
__global__ __launch_bounds__(256, 5)
void gemm_k(const bf16* __restrict__ A, int lda,
            const bf16* __restrict__ Bw, int ldb, int ksteps,
            bf16* __restrict__ zpnw, const float* __restrict__ bias1,
            bf16* __restrict__ Anext)
{
  __shared__ bf16 lA[2][128*32];
  __shared__ bf16 lB[2][96*32];
  const int tid = threadIdx.x, wid = tid>>6, lane = tid&63;
  const int l15 = lane&15, l4 = lane>>4;
  const int bx = blockIdx.x, by = blockIdx.y;
  const int n0 = bx*96, m0 = by*128;

  f32x4 acc[2][6];
  #pragma unroll
  for (int i=0;i<2;++i)
    #pragma unroll
    for (int j=0;j<6;++j) acc[i][j] = (f32x4){0.f,0.f,0.f,0.f};

  auto STAGE = [&](int buf, int ks){
    const int k0 = ks*32;
    const bf16* gA = A + (size_t)m0*lda + k0;
    #pragma unroll
    for (int r=0; r<2; ++r){
      int q = r*256 + tid;
      int row = q>>2, slot = q&3;
      int sg = slot ^ ((row>>1)&3);
      const bf16* gp = gA + (size_t)row*lda + sg*8;
      bf16* lp = &lA[buf][(size_t)(r*256 + wid*64)*8];
      __builtin_amdgcn_global_load_lds((as1cv)gp, (as3v)lp, 16, 0, 0);
    }
    const bf16* gB = Bw + (size_t)n0*ldb + k0;
    {
      int q = tid;
      int row = q>>2, slot = q&3;
      int sg = slot ^ ((row>>1)&3);
      const bf16* gp = gB + (size_t)row*ldb + sg*8;
      bf16* lp = &lB[buf][(size_t)(wid*64)*8];
      __builtin_amdgcn_global_load_lds((as1cv)gp, (as3v)lp, 16, 0, 0);
    }
    if (tid < 128){
      int q = 256 + tid;
      int row = q>>2, slot = q&3;
      int sg = slot ^ ((row>>1)&3);
      const bf16* gp = gB + (size_t)row*ldb + sg*8;
      bf16* lp = &lB[buf][(size_t)(256 + wid*64)*8];
      __builtin_amdgcn_global_load_lds((as1cv)gp, (as3v)lp, 16, 0, 0);
    }
  };

  const int sl = (l4 ^ ((l15>>1)&3))*8;
  int cur = 0;
  STAGE(0, 0);
  for (int ks=0; ks<ksteps; ++ks){
    __syncthreads();
    if (ks+1 < ksteps) STAGE(cur^1, ks+1);
    bf16x8 af0 = *(const bf16x8*)&lA[cur][(wid*32 +  0 + l15)*32 + sl];
    bf16x8 af1 = *(const bf16x8*)&lA[cur][(wid*32 + 16 + l15)*32 + sl];
    #pragma unroll
    for (int cf=0; cf<6; ++cf){
      bf16x8 bfr = *(const bf16x8*)&lB[cur][(cf*16 + l15)*32 + sl];
      acc[0][cf] = __builtin_amdgcn_mfma_f32_16x16x32_bf16(af0, bfr, acc[0][cf], 0,0,0);
      acc[1][cf] = __builtin_amdgcn_mfma_f32_16x16x32_bf16(af1, bfr, acc[1][cf], 0,0,0);
    }
    cur ^= 1;
  }

  const int rbase = m0 + wid*32 + l4*4;
  #pragma unroll
  for (int rf=0; rf<2; ++rf)
    #pragma unroll
    for (int cf=0; cf<6; ++cf){
      int jn = n0 + cf*16 + l15;
      if (jn < HD){
        float bi = bias1[jn];
        #pragma unroll
        for (int reg=0; reg<4; ++reg){
          int b = rbase + rf*16 + reg;
          if constexpr (EP == 0)
            zpnw[(size_t)b*HD + jn] = (bf16)(acc[rf][cf][reg] + bi);
          else
            Anext[(size_t)b*KAUG + jn] = (bf16)tanhfast(acc[rf][cf][reg] + bi);
        }
      }
    }
}

// ---------------- main step GEMM: tile 128x192, BK=64, 4 waves (2M x 2N) ----------------
// R17 geometry + R17 XCD map; ONLY change vs R17: counted-vmcnt pipeline.
// STAGE(k+1) -> s_waitcnt vmcnt(10) (waits buffer-k's 10/thread loads, issued
// one full iteration earlier) -> s_barrier -> 48 MFMA -> fence -> s_barrier.
__global__ __launch_bounds__(256, 2)
void gru_step(const bf16* __restrict__ Acur, const bf16* __restrict__ Wg,
              const bf16* __restrict__ zpn, const float* __restrict__ biasz,
              const float* __restrict__ bhhn, const float* __restrict__ Wih,
              const float* __restrict__ cond, bf16* __restrict__ Anext,
              const float* __restrict__ bout, float* __restrict__ outg, int t)
{
  __shared__ bf16 lA[2][128*64];
  __shared__ bf16 lB[2][192*64];
  const int tid = threadIdx.x, wid = tid>>6, lane = tid&63;
  const int l15 = lane&15, l4 = lane>>4;
  const int wm = wid>>1, wn = wid&1;

  // R17 XCD-bijective map: XCD x owns by in [4x,4x+4), all bx
  const int bid = blockIdx.x;
  const int x = bid & 7, k = bid >> 3;   // k 0..67
  const int bx = k >> 2;                 // 0..16
  const int by = x*4 + (k & 3);          // 0..31
  const int n0 = bx*192, m0 = by*128;

  f32x4 acc[4][6];
  #pragma unroll
  for (int i=0;i<4;++i)
    #pragma unroll
    for (int j=0;j<6;++j) acc[i][j] = (f32x4){0.f,0.f,0.f,0.f};

  // stage K-tile (64 cols): uniform 10 loads/thread (4 A + 6 B, 16B each).
  // LDS dest linear; global source 16B-slot XOR-swizzled: sg = slot ^ (row&7).
  auto STAGE = [&](int buf, int ks){
    const int k0 = ks*64;
    const bf16* gA = Acur + (size_t)m0*KAUG + k0;
    #pragma unroll
    for (int r=0; r<4; ++r){
      int q = r*256 + tid;
      int row = q>>3, slot = q&7;
      int sg = slot ^ (row&7);
      const bf16* gp = gA + (size_t)row*KAUG + sg*8;
      bf16* lp = &lA[buf][(size_t)(r*256 + wid*64)*8];
      __builtin_amdgcn_global_load_lds((as1cv)gp, (as3v)lp, 16, 0, 0);
    }
    const bf16* gB = Wg + (size_t)n0*KAUG + k0;
    #pragma unroll
    for (int r=0; r<6; ++r){
      int q = r*256 + tid;
      int row = q>>3, slot = q&7;
      int sg = slot ^ (row&7);
      const bf16* gp = gB + (size_t)row*KAUG + sg*8;
      bf16* lp = &lB[buf][(size_t)(r*256 + wid*64)*8];
      __builtin_amdgcn_global_load_lds((as1cv)gp, (as3v)lp, 16, 0, 0);
    }
  };

  int cur = 0;
  STAGE(0, 0);
  for (int ks=0; ks<KS64; ++ks){
    if (ks+1 < KS64){
      STAGE(cur^1, ks+1);                // 20 outstanding/thread
      asm volatile("s_waitcnt vmcnt(10)" ::: "memory");   // wait cur's 10 only
    } else {
      asm volatile("s_waitcnt vmcnt(0)" ::: "memory");
    }
    __builtin_amdgcn_s_barrier();        // buf[cur] ready on all waves
    #pragma unroll
    for (int kk=0; kk<2; ++kk){
      bf16x8 af[4];
      #pragma unroll
      for (int mf=0; mf<4; ++mf){
        int row = wm*64 + mf*16 + l15;
        int sp = (kk*4 + l4) ^ (row&7);
        af[mf] = *(const bf16x8*)&lA[cur][row*64 + sp*8];
      }
      #pragma unroll
      for (int nf=0; nf<6; ++nf){
        int row = wn*96 + nf*16 + l15;
        int sp = (kk*4 + l4) ^ (row&7);
        bf16x8 bfr = *(const bf16x8*)&lB[cur][row*64 + sp*8];
        acc[0][nf] = __builtin_amdgcn_mfma_f32_16x16x32_bf16(af[0], bfr, acc[0][nf], 0,0,0);
        acc[1][nf] = __builtin_amdgcn_mfma_f32_16x16x32_bf16(af[1], bfr, acc[1][nf], 0,0,0);
        acc[2][nf] = __builtin_amdgcn_mfma_f32_16x16x32_bf16(af[2], bfr, acc[2][nf], 0,0,0);
        acc[3][nf] = __builtin_amdgcn_mfma_f32_16x16x32_bf16(af[3], bfr, acc[3][nf], 0,0,0);
      }
    }
    asm volatile("" ::: "memory");       // keep ds_reads before the WAR barrier
    __builtin_amdgcn_s_barrier();        // all reads of buf[cur] done
    cur ^= 1;
  }

  const int rbase = m0 + wm*64 + l4*4;   // + mf*16 + reg

  if (bx == 16){
    // out-projection tile: wn==0 waves cover cols 3072..3167 (Wout rows at 3072)
    if (wn == 0 && t > 0 && l15 < CD){
      float bo = bout[l15];
      #pragma unroll
      for (int mf=0; mf<4; ++mf){
        #pragma unroll
        for (int reg=0; reg<4; ++reg){
          int b = rbase + mf*16 + reg;
          outg[((size_t)b*TT + (t-1))*CD + l15] = sigm(acc[mf][0][reg] + bo);
        }
      }
    }
  } else {
    const int jg = bx*2 + wn;            // gate group 0..31
    // n-gate feed weights: W_ih[2048+jn, 0:12]
    float wfn[2][12];
    #pragma unroll
    for (int jf=0; jf<2; ++jf){
      int jn = jg*32 + jf*16 + l15;
      const f4* wr = (const f4*)(Wih + (size_t)(2048 + jn)*140);
      f4 w0 = wr[0], w1 = wr[1], w2 = wr[2];
      #pragma unroll
      for (int c=0;c<4;++c){ wfn[jf][c]=w0[c]; wfn[jf][4+c]=w1[c]; wfn[jf][8+c]=w2[c]; }
    }
    #pragma unroll
    for (int mf=0; mf<4; ++mf){
      #pragma unroll
      for (int reg=0; reg<4; ++reg){
        int b = rbase + mf*16 + reg;
        const bf16* fr = Acur + (size_t)b*KAUG + 1024;
        bf16x8 f8 = *(const bf16x8*)fr;
        float fd[12];
        #pragma unroll
        for (int c=0;c<8;++c) fd[c] = (float)f8[c];
        #pragma unroll
        for (int c=8;c<12;++c) fd[c] = (float)fr[c];
        #pragma unroll
        for (int jf=0; jf<2; ++jf){
          int jn = jg*32 + jf*16 + l15;
          int np = jg*96 + jf*16 + l15;
          float aR = acc[mf][jf  ][reg] + biasz[np];
          float aZ = acc[mf][2+jf][reg] + biasz[np+32];
          float hN = acc[mf][4+jf][reg] + bhhn[jn];
          float iN = (float)zpn[(size_t)b*HD + jn];
          float fdot = 0.0f;
          #pragma unroll
          for (int c=0;c<12;++c) fdot += fd[c]*wfn[jf][c];
          float r = sigm(aR);
          float u = sigm(aZ);
          float nn = tanhfast(iN + fdot + r*hN);
          float hp = (float)Acur[(size_t)b*KAUG + jn];
          float hv = (1.0f-u)*nn + u*hp;
          Anext[(size_t)b*KAUG + jn] = (bf16)hv;
        }
      }
    }
    // feed columns of A_next for step t+1 : condition[:, t, :]
    if (bx == 0){
      for (int i = tid; i < 128*CD; i += 256){
        int rr = i/CD, c = i - rr*CD;
        int b = m0 + rr;
        Anext[(size_t)b*KAUG + 1024 + c] = (bf16)cond[((size_t)b*TT + t)*CD + c];
      }
    }
  }
}

// ---------------- final-step output projection ----------------
__global__ __launch_bounds__(256)
void out_k(const bf16* __restrict__ hstate, const float* __restrict__ Wout,
           const float* __restrict__ bout, float* __restrict__ out, int t)
{
  __shared__ float sw[CD*HD];
  __shared__ float sb[CD];
  const int tid = threadIdx.x;
  for (int i=tid; i<CD*HD; i+=256) sw[i] = Wout[i];
  if (tid < CD) sb[tid] = bout[tid];
  __syncthreads();
  const int wid = tid>>6, lane = tid&63;
  const int b0 = blockIdx.x*8 + wid*2;
  for (int rr=0; rr<2; ++rr){
    int b = b0 + rr;
    const bf16* hr = hstate + (size_t)b*KAUG;
    float p[CD];
    #pragma unroll
    for (int c=0;c<CD;++c) p[c] = 0.0f;
    #pragma unroll
    for (int j=0;j<8;++j){
      int idx = lane*2 + j*128;
      bf16x2 hv = *(const bf16x2*)&hr[idx];
      float h0 = (float)hv[0], h1 = (float)hv[1];
      #pragma unroll
      for (int c=0;c<CD;++c) p[c] += h0*sw[c*HD + idx] + h1*sw[c*HD + idx + 1];
    }
    #pragma unroll
    for (int c=0;c<CD;++c){
      float v = p[c];
      #pragma unroll
      for (int m=32;m>=1;m>>=1) v += __shfl_xor(v, m, 64);
      if (lane == 0) out[((size_t)b*TT + t)*CD + c] = sigm(v + sb[c]);
    }
  }
}

// ---------------- launch ----------------
extern "C" void kernel_launch(void* const* d_in, const int* in_sizes, int n_in,
                              void* d_out, int out_size, void* d_ws, size_t ws_size,
                              hipStream_t stream) {
  const float* z     = (const float*)d_in[0];
  const float* cond  = (const float*)d_in[1];
  const float* Wih   = (const float*)d_in[3];
  const float* Whh   = (const float*)d_in[4];
  const float* bih   = (const float*)d_in[5];
  const float* bhh   = (const float*)d_in[6];
  const float* Winit = (const float*)d_in[7];
  const float* binit = (const float*)d_in[8];
  const float* Wout  = (const float*)d_in[9];
  const float* bout  = (const float*)d_in[10];
  float* out = (float*)d_out;

  char* ws = (char*)d_ws;
  size_t off = 0;
  auto carve = [&](size_t bytes)->char*{
    char* p = ws + off; off += (bytes + 255) & ~(size_t)255; return p;
  };
  bf16*  Wg    = (bf16*) carve((size_t)NGP*KAUG*2);
  bf16*  Wzn   = (bf16*) carve((size_t)NPH0B*Z1D*2);
  bf16*  Wi0   = (bf16*) carve((size_t)NPH0B*Z1D*2);
  bf16*  zbf   = (bf16*) carve((size_t)BB*Z1D*2);
  float* biasz = (float*)carve((size_t)N3H*4);
  float* bhhn  = (float*)carve((size_t)HD*4);
  float* bihn  = (float*)carve((size_t)HD*4);
  bf16*  zpn   = (bf16*) carve((size_t)BB*HD*2);
  bf16*  A0    = (bf16*) carve((size_t)BB*KAUG*2);
  bf16*  A1    = (bf16*) carve((size_t)BB*KAUG*2);

  // prep
  {
    long total = (long)NGP*KAUG + 2L*NPH0B*Z1D + (long)BB*Z1D + N3H + 2*HD
               + 2L*BB*ACOLS;
    int blocks = (int)((total + 255)/256);
    prep_k<<<blocks, 256, 0, stream>>>(z, Wih, Whh, bih, bhh, Winit, Wout,
                                       Wg, Wzn, Wi0, zbf, biasz, bhhn, bihn,
                                       A0, A1);
  }
  // zpn : n-gate z-projection + bih_n -> bf16. M=4096, N=1024(pad), K=128
  gemm_k<0><<<dim3(11,32), 256, 0, stream>>>(zbf, Z1D, Wzn, Z1D, 4,
      zpn, bihn, nullptr);
  // h0 : tanh(z@Winit^T + binit) -> A0 state cols. M=4096, N=1024(pad), K=128
  gemm_k<1><<<dim3(11,32), 256, 0, stream>>>(zbf, Z1D, Wi0, Z1D, 4,
      nullptr, binit, A0);

  for (int t = 0; t < TT; ++t){
    const bf16* Ac = (t & 1) ? A1 : A0;
    bf16*       An = (t & 1) ? A0 : A1;
    gru_step<<<544, 256, 0, stream>>>(Ac, Wg, zpn, biasz, bhhn, Wih, cond,
                                      An, bout, out, t);
  }
  // final step t=31: state is in A0 (t=31 odd -> An=A0)
  out_k<<<512, 256, 0, stream>>>(A0, Wout, bout, out, 31);
}

// Round 20
// 1604.622 us; speedup vs baseline: 1.2364x; 1.1528x over previous
//
#include <hip/hip_runtime.h>
#include <stdint.h>

#define BB    4096   // batch
#define Z1D   128
#define CD    12     // cond dim
#define HD    1024   // hidden
#define TT    32     // steps
#define N3H   3072   // 3*HD
#define KAUG  1216   // 1024 h + 12 feed + 128 z + 52 pad = 19*64
#define NGP   3072   // Wg rows: gates only (16 x 192)
#define NPH0B 1088   // padded rows for prologue B matrices
#define ACOLS 192    // A-state cols re-inited by prep (1024..1216)
#define KS64  19     // K-steps (BK=64) in main GEMM

typedef __bf16 bf16;
typedef __bf16 bf16x2 __attribute__((ext_vector_type(2)));
typedef __bf16 bf16x8 __attribute__((ext_vector_type(8)));
typedef float  f32x4  __attribute__((ext_vector_type(4)));
typedef float  f4     __attribute__((ext_vector_type(4)));

typedef const __attribute__((address_space(1))) void* as1cv;
typedef __attribute__((address_space(3))) void* as3v;

__device__ __forceinline__ float sigm(float x){ return 1.0f/(1.0f+__expf(-x)); }
__device__ __forceinline__ float tanhfast(float x){ return 1.0f - 2.0f/(1.0f+__expf(2.0f*x)); }

// interleaved column index n' -> original gate row (g*1024 + jn)
// 96-wide groups: [r(32) | z(32) | n_h(32)] for 32 consecutive hidden cols
__device__ __forceinline__ int rowOfN(int np, int& g){
  int jb = np/96; int r = np - jb*96; g = r>>5; int jl = r&31;
  return g*1024 + jb*32 + jl;
}

// ---------------- prep: weight conversion / layout / state init ----------------
__global__ __launch_bounds__(256)
void prep_k(const float* __restrict__ z, const float* __restrict__ Wih,
            const float* __restrict__ Whh, const float* __restrict__ bih,
            const float* __restrict__ bhh, const float* __restrict__ Winit,
            const float* __restrict__ Wout,
            bf16* __restrict__ Wg, bf16* __restrict__ WoB,
            bf16* __restrict__ Wzn, bf16* __restrict__ Wi0,
            bf16* __restrict__ zbf, float* __restrict__ biasz,
            float* __restrict__ bhhn, float* __restrict__ bihn,
            bf16* __restrict__ A0, bf16* __restrict__ A1)
{
  const int N1 = NGP*KAUG;       // Wg: gates interleaved
  const int N8 = 16*HD;          // WoB: Wout rows (12) + 4 zero pad
  const int N2 = NPH0B*Z1D;      // Wzn
  const int N3 = NPH0B*Z1D;      // Wi0
  const int N4 = BB*Z1D;         // zbf
  const int N5 = N3H;            // biasz (r,z: bih+bhh)
  const int N6 = HD;             // bhhn
  const int N6b= HD;             // bihn
  const int N7 = 2*BB*ACOLS;     // A0/A1 init: cols 1024..1216 only
  int idx = blockIdx.x*256 + threadIdx.x;
  if (idx < N1){
    int np = idx/KAUG, k = idx - np*KAUG;
    int g; int row = rowOfN(np, g);
    float v = 0.0f;
    if (k < 1024) v = Whh[(size_t)row*HD + k];
    else if (g < 2){
      if (k < 1036)      v = Wih[(size_t)row*140 + (k-1024)];       // feed cols
      else if (k < 1164) v = Wih[(size_t)row*140 + 12 + (k-1036)];  // z cols
    }
    Wg[idx] = (bf16)v;
    return;
  }
  idx -= N1;
  if (idx < N8){
    int c = idx/HD, k = idx - c*HD;
    WoB[idx] = (c < CD) ? (bf16)Wout[(size_t)c*HD + k] : (bf16)0.0f;
    return;
  }
  idx -= N8;
  if (idx < N2){
    int jn = idx/Z1D, kk = idx - jn*Z1D;
    Wzn[idx] = (jn < HD) ? (bf16)Wih[(size_t)(2048+jn)*140 + 12 + kk] : (bf16)0.0f;
    return;
  }
  idx -= N2;
  if (idx < N3){
    int jn = idx/Z1D, kk = idx - jn*Z1D;
    Wi0[idx] = (jn < HD) ? (bf16)Winit[(size_t)jn*Z1D + kk] : (bf16)0.0f;
    return;
  }
  idx -= N3;
  if (idx < N4){ zbf[idx] = (bf16)z[idx]; return; }
  idx -= N4;
  if (idx < N5){
    int g; int row = rowOfN(idx, g);
    biasz[idx] = (g < 2) ? (bih[row] + bhh[row]) : 0.0f;
    return;
  }
  idx -= N5;
  if (idx < N6){ bhhn[idx] = bhh[2048 + idx]; return; }
  idx -= N6;
  if (idx < N6b){ bihn[idx] = bih[2048 + idx]; return; }
  idx -= N6b;
  if (idx < N7){
    int j = (idx < BB*ACOLS) ? idx : idx - BB*ACOLS;
    int b = j / ACOLS, kk = j - b*ACOLS;
    int k = 1024 + kk;                   // feed(12) | z(128) | pad(52)
    bf16 v = (bf16)0.0f;
    if (k >= 1036 && k < 1164) v = (bf16)z[(size_t)b*Z1D + (k-1036)];
    if (idx < BB*ACOLS) A0[(size_t)b*KAUG + k] = v;
    else                A1[(size_t)b*KAUG + k] = v;
  }
}

// ---------------- prologue GEMM (zpn / h0), proven R9 structure, BK=32 ----------------
template<int EP>
__global__ __launch_bounds__(256, 5)
void gemm_k(const bf16* __restrict__ A, int lda,
            const bf16* __restrict__ Bw, int ldb, int ksteps,
            bf16* __restrict__ zpnw, const float* __restrict__ bias1,
            bf16* __restrict__ Anext)
{
  __shared__ bf16 lA[2][128*32];
  __shared__ bf16 lB[2][96*32];
  const int tid = threadIdx.x, wid = tid>>6, lane = tid&63;
  const int l15 = lane&15, l4 = lane>>4;
  const int bx = blockIdx.x, by = blockIdx.y;
  const int n0 = bx*96, m0 = by*128;

  f32x4 acc[2][6];
  #pragma unroll
  for (int i=0;i<2;++i)
    #pragma unroll
    for (int j=0;j<6;++j) acc[i][j] = (f32x4){0.f,0.f,0.f,0.f};

  auto STAGE = [&](int buf, int ks){
    const int k0 = ks*32;
    const bf16* gA = A + (size_t)m0*lda + k0;
    #pragma unroll
    for (int r=0; r<2; ++r){
      int q = r*256 + tid;
      int row = q>>2, slot = q&3;
      int sg = slot ^ ((row>>1)&3);
      const bf16* gp = gA + (size_t)row*lda + sg*8;
      bf16* lp = &lA[buf][(size_t)(r*256 + wid*64)*8];
      __builtin_amdgcn_global_load_lds((as1cv)gp, (as3v)lp, 16, 0, 0);
    }
    const bf16* gB = Bw + (size_t)n0*ldb + k0;
    {
      int q = tid;
      int row = q>>2, slot = q&3;
      int sg = slot ^ ((row>>1)&3);
      const bf16* gp = gB + (size_t)row*ldb + sg*8;
      bf16* lp = &lB[buf][(size_t)(wid*64)*8];
      __builtin_amdgcn_global_load_lds((as1cv)gp, (as3v)lp, 16, 0, 0);
    }
    if (tid < 128){
      int q = 256 + tid;
      int row = q>>2, slot = q&3;
      int sg = slot ^ ((row>>1)&3);
      const bf16* gp = gB + (size_t)row*ldb + sg*8;
      bf16* lp = &lB[buf][(size_t)(256 + wid*64)*8];
      __builtin_amdgcn_global_load_lds((as1cv)gp, (as3v)lp, 16, 0, 0);
    }
  };

  const int sl = (l4 ^ ((l15>>1)&3))*8;
  int cur = 0;
  STAGE(0, 0);
  for (int ks=0; ks<ksteps; ++ks){
    __syncthreads();
    if (ks+1 < ksteps) STAGE(cur^1, ks+1);
    bf16x8 af0 = *(const bf16x8*)&lA[cur][(wid*32 +  0 + l15)*32 + sl];
    bf16x8 af1 = *(const bf16x8*)&lA[cur][(wid*32 + 16 + l15)*32 + sl];
    #pragma unroll
    for (int cf=0; cf<6; ++cf){
      bf16x8 bfr = *(const bf16x8*)&lB[cur][(cf*16 + l15)*32 + sl];
      acc[0][cf] = __builtin_amdgcn_mfma_f32_16x16x32_bf16(af0, bfr, acc[0][cf], 0,0,0);
      acc[1][cf] = __builtin_amdgcn_mfma_f32_16x16x32_bf16(af1, bfr, acc[1][cf], 0,0,0);
    }
    cur ^= 1;
  }

  const int rbase = m0 + wid*32 + l4*4;
  #pragma unroll
  for (int rf=0; rf<2; ++rf)
    #pragma unroll
    for (int cf=0; cf<6; ++cf){
      int jn = n0 + cf*16 + l15;
      if (jn < HD){
        float bi = bias1[jn];
        #pragma unroll
        for (int reg=0; reg<4; ++reg){
          int b = rbase + rf*16 + reg;
          if constexpr (EP == 0)
            zpnw[(size_t)b*HD + jn] = (bf16)(acc[rf][cf][reg] + bi);
          else
            Anext[(size_t)b*KAUG + jn] = (bf16)tanhfast(acc[rf][cf][reg] + bi);
        }
      }
    }
}

// ---------------- main step GEMM: tile 256x192, BK=64, 8 waves (4M x 2N) ----------------
// Grid EXACTLY 256 = one generation at 1 block/CU (LDS 112 KB). Wave = 64 rows
// x 96 cols (lane-local [r|z|n] epilogue, jg = bx*2+wn). R17-proven loop:
// single __syncthreads per K-step, depth-1 prefetch, XOR swizzle slot^(row&7).
// bx==0 / wn==0 waves additionally accumulate out[:,t-1,:] via WoB fragments.
__global__ __launch_bounds__(512, 1)
void gru_step(const bf16* __restrict__ Acur, const bf16* __restrict__ Wg,
              const bf16* __restrict__ WoB, const bf16* __restrict__ zpn,
              const float* __restrict__ biasz, const float* __restrict__ bhhn,
              const float* __restrict__ Wih, const float* __restrict__ cond,
              bf16* __restrict__ Anext, const float* __restrict__ bout,
              float* __restrict__ outg, int t)
{
  __shared__ bf16 lA[2][256*64];
  __shared__ bf16 lB[2][192*64];
  const int tid = threadIdx.x, wid = tid>>6, lane = tid&63;
  const int l15 = lane&15, l4 = lane>>4;
  const int wm = wid>>1, wn = wid&1;

  // XCD map over 256 blocks: XCD x owns by {2x,2x+1} x all bx (A-slice L2-resident)
  const int bid = blockIdx.x;
  const int x = bid & 7, k = bid >> 3;   // k 0..31
  const int bx = k >> 1;                 // 0..15
  const int by = x*2 + (k & 1);          // 0..15
  const int n0 = bx*192, m0 = by*256;

  f32x4 acc[4][6];
  #pragma unroll
  for (int i=0;i<4;++i)
    #pragma unroll
    for (int j=0;j<6;++j) acc[i][j] = (f32x4){0.f,0.f,0.f,0.f};

  const bool doOut = (bx == 0) && (wn == 0) && (t > 0);
  f32x4 acco[4];
  #pragma unroll
  for (int i=0;i<4;++i) acco[i] = (f32x4){0.f,0.f,0.f,0.f};

  // stage K-tile (64 cols): uniform 7 loads/thread (4 A + 3 B, 16B each).
  // LDS dest linear; global source 16B-slot XOR-swizzled: sg = slot ^ (row&7).
  auto STAGE = [&](int buf, int ks){
    const int k0 = ks*64;
    const bf16* gA = Acur + (size_t)m0*KAUG + k0;
    #pragma unroll
    for (int r=0; r<4; ++r){
      int q = r*512 + tid;
      int row = q>>3, slot = q&7;
      int sg = slot ^ (row&7);
      const bf16* gp = gA + (size_t)row*KAUG + sg*8;
      bf16* lp = &lA[buf][(size_t)(r*512 + wid*64)*8];
      __builtin_amdgcn_global_load_lds((as1cv)gp, (as3v)lp, 16, 0, 0);
    }
    const bf16* gB = Wg + (size_t)n0*KAUG + k0;
    #pragma unroll
    for (int r=0; r<3; ++r){
      int q = r*512 + tid;
      int row = q>>3, slot = q&7;
      int sg = slot ^ (row&7);
      const bf16* gp = gB + (size_t)row*KAUG + sg*8;
      bf16* lp = &lB[buf][(size_t)(r*512 + wid*64)*8];
      __builtin_amdgcn_global_load_lds((as1cv)gp, (as3v)lp, 16, 0, 0);
    }
  };

  int cur = 0;
  STAGE(0, 0);
  for (int ks=0; ks<KS64; ++ks){
    __syncthreads();                     // buf[cur] ready; prior reads of cur^1 done
    if (ks+1 < KS64) STAGE(cur^1, ks+1);
    #pragma unroll
    for (int kk=0; kk<2; ++kk){
      bf16x8 af[4];
      #pragma unroll
      for (int mf=0; mf<4; ++mf){
        int row = wm*64 + mf*16 + l15;
        int sp = (kk*4 + l4) ^ (row&7);
        af[mf] = *(const bf16x8*)&lA[cur][row*64 + sp*8];
      }
      #pragma unroll
      for (int nf=0; nf<6; ++nf){
        int row = wn*96 + nf*16 + l15;
        int sp = (kk*4 + l4) ^ (row&7);
        bf16x8 bfr = *(const bf16x8*)&lB[cur][row*64 + sp*8];
        acc[0][nf] = __builtin_amdgcn_mfma_f32_16x16x32_bf16(af[0], bfr, acc[0][nf], 0,0,0);
        acc[1][nf] = __builtin_amdgcn_mfma_f32_16x16x32_bf16(af[1], bfr, acc[1][nf], 0,0,0);
        acc[2][nf] = __builtin_amdgcn_mfma_f32_16x16x32_bf16(af[2], bfr, acc[2][nf], 0,0,0);
        acc[3][nf] = __builtin_amdgcn_mfma_f32_16x16x32_bf16(af[3], bfr, acc[3][nf], 0,0,0);
      }
      if (doOut && ks < 16){             // out-projection extra (Wout K=1024)
        bf16x8 wf = *(const bf16x8*)&WoB[(size_t)l15*HD + ks*64 + kk*32 + l4*8];
        acco[0] = __builtin_amdgcn_mfma_f32_16x16x32_bf16(af[0], wf, acco[0], 0,0,0);
        acco[1] = __builtin_amdgcn_mfma_f32_16x16x32_bf16(af[1], wf, acco[1], 0,0,0);
        acco[2] = __builtin_amdgcn_mfma_f32_16x16x32_bf16(af[2], wf, acco[2], 0,0,0);
        acco[3] = __builtin_amdgcn_mfma_f32_16x16x32_bf16(af[3], wf, acco[3], 0,0,0);
      }
    }
    cur ^= 1;
  }

  const int rbase = m0 + wm*64 + l4*4;   // + mf*16 + reg

  {
    const int jg = bx*2 + wn;            // gate group 0..31
    // n-gate feed weights: W_ih[2048+jn, 0:12]
    float wfn[2][12];
    #pragma unroll
    for (int jf=0; jf<2; ++jf){
      int jn = jg*32 + jf*16 + l15;
      const f4* wr = (const f4*)(Wih + (size_t)(2048 + jn)*140);
      f4 w0 = wr[0], w1 = wr[1], w2 = wr[2];
      #pragma unroll
      for (int c=0;c<4;++c){ wfn[jf][c]=w0[c]; wfn[jf][4+c]=w1[c]; wfn[jf][8+c]=w2[c]; }
    }
    #pragma unroll
    for (int mf=0; mf<4; ++mf){
      #pragma unroll
      for (int reg=0; reg<4; ++reg){
        int b = rbase + mf*16 + reg;
        const bf16* fr = Acur + (size_t)b*KAUG + 1024;
        bf16x8 f8 = *(const bf16x8*)fr;
        float fd[12];
        #pragma unroll
        for (int c=0;c<8;++c) fd[c] = (float)f8[c];
        #pragma unroll
        for (int c=8;c<12;++c) fd[c] = (float)fr[c];
        #pragma unroll
        for (int jf=0; jf<2; ++jf){
          int jn = jg*32 + jf*16 + l15;
          int np = jg*96 + jf*16 + l15;
          float aR = acc[mf][jf  ][reg] + biasz[np];
          float aZ = acc[mf][2+jf][reg] + biasz[np+32];
          float hN = acc[mf][4+jf][reg] + bhhn[jn];
          float iN = (float)zpn[(size_t)b*HD + jn];
          float fdot = 0.0f;
          #pragma unroll
          for (int c=0;c<12;++c) fdot += fd[c]*wfn[jf][c];
          float r = sigm(aR);
          float u = sigm(aZ);
          float nn = tanhfast(iN + fdot + r*hN);
          float hp = (float)Acur[(size_t)b*KAUG + jn];
          float hv = (1.0f-u)*nn + u*hp;
          Anext[(size_t)b*KAUG + jn] = (bf16)hv;
        }
      }
    }
  }
  // out-projection write: out[:, t-1, :]
  if (doOut){
    int c = l15;
    if (c < CD){
      float bo = bout[c];
      #pragma unroll
      for (int mf=0; mf<4; ++mf){
        #pragma unroll
        for (int reg=0; reg<4; ++reg){
          int b = rbase + mf*16 + reg;
          outg[((size_t)b*TT + (t-1))*CD + c] = sigm(acco[mf][reg] + bo);
        }
      }
    }
  }
  // feed columns of A_next for step t+1 : condition[:, t, :]
  if (bx == 0){
    for (int i = tid; i < 256*CD; i += 512){
      int rr = i/CD, c = i - rr*CD;
      int b = m0 + rr;
      Anext[(size_t)b*KAUG + 1024 + c] = (bf16)cond[((size_t)b*TT + t)*CD + c];
    }
  }
}

// ---------------- final-step output projection ----------------
__global__ __launch_bounds__(256)
void out_k(const bf16* __restrict__ hstate, const float* __restrict__ Wout,
           const float* __restrict__ bout, float* __restrict__ out, int t)
{
  __shared__ float sw[CD*HD];
  __shared__ float sb[CD];
  const int tid = threadIdx.x;
  for (int i=tid; i<CD*HD; i+=256) sw[i] = Wout[i];
  if (tid < CD) sb[tid] = bout[tid];
  __syncthreads();
  const int wid = tid>>6, lane = tid&63;
  const int b0 = blockIdx.x*8 + wid*2;
  for (int rr=0; rr<2; ++rr){
    int b = b0 + rr;
    const bf16* hr = hstate + (size_t)b*KAUG;
    float p[CD];
    #pragma unroll
    for (int c=0;c<CD;++c) p[c] = 0.0f;
    #pragma unroll
    for (int j=0;j<8;++j){
      int idx = lane*2 + j*128;
      bf16x2 hv = *(const bf16x2*)&hr[idx];
      float h0 = (float)hv[0], h1 = (float)hv[1];
      #pragma unroll
      for (int c=0;c<CD;++c) p[c] += h0*sw[c*HD + idx] + h1*sw[c*HD + idx + 1];
    }
    #pragma unroll
    for (int c=0;c<CD;++c){
      float v = p[c];
      #pragma unroll
      for (int m=32;m>=1;m>>=1) v += __shfl_xor(v, m, 64);
      if (lane == 0) out[((size_t)b*TT + t)*CD + c] = sigm(v + sb[c]);
    }
  }
}

// ---------------- launch ----------------
extern "C" void kernel_launch(void* const* d_in, const int* in_sizes, int n_in,
                              void* d_out, int out_size, void* d_ws, size_t ws_size,
                              hipStream_t stream) {
  const float* z     = (const float*)d_in[0];
  const float* cond  = (const float*)d_in[1];
  const float* Wih   = (const float*)d_in[3];
  const float* Whh   = (const float*)d_in[4];
  const float* bih   = (const float*)d_in[5];
  const float* bhh   = (const float*)d_in[6];
  const float* Winit = (const float*)d_in[7];
  const float* binit = (const float*)d_in[8];
  const float* Wout  = (const float*)d_in[9];
  const float* bout  = (const float*)d_in[10];
  float* out = (float*)d_out;

  char* ws = (char*)d_ws;
  size_t off = 0;
  auto carve = [&](size_t bytes)->char*{
    char* p = ws + off; off += (bytes + 255) & ~(size_t)255; return p;
  };
  bf16*  Wg    = (bf16*) carve((size_t)NGP*KAUG*2);
  bf16*  WoB   = (bf16*) carve((size_t)16*HD*2);
  bf16*  Wzn   = (bf16*) carve((size_t)NPH0B*Z1D*2);
  bf16*  Wi0   = (bf16*) carve((size_t)NPH0B*Z1D*2);
  bf16*  zbf   = (bf16*) carve((size_t)BB*Z1D*2);
  float* biasz = (float*)carve((size_t)N3H*4);
  float* bhhn  = (float*)carve((size_t)HD*4);
  float* bihn  = (float*)carve((size_t)HD*4);
  bf16*  zpn   = (bf16*) carve((size_t)BB*HD*2);
  bf16*  A0    = (bf16*) carve((size_t)BB*KAUG*2);
  bf16*  A1    = (bf16*) carve((size_t)BB*KAUG*2);

  // prep
  {
    long total = (long)NGP*KAUG + 16L*HD + 2L*NPH0B*Z1D + (long)BB*Z1D + N3H
               + 2*HD + 2L*BB*ACOLS;
    int blocks = (int)((total + 255)/256);
    prep_k<<<blocks, 256, 0, stream>>>(z, Wih, Whh, bih, bhh, Winit, Wout,
                                       Wg, WoB, Wzn, Wi0, zbf, biasz, bhhn, bihn,
                                       A0, A1);
  }
  // zpn : n-gate z-projection + bih_n -> bf16. M=4096, N=1024(pad), K=128
  gemm_k<0><<<dim3(11,32), 256, 0, stream>>>(zbf, Z1D, Wzn, Z1D, 4,
      zpn, bihn, nullptr);
  // h0 : tanh(z@Winit^T + binit) -> A0 state cols. M=4096, N=1024(pad), K=128
  gemm_k<1><<<dim3(11,32), 256, 0, stream>>>(zbf, Z1D, Wi0, Z1D, 4,
      nullptr, binit, A0);

  for (int t = 0; t < TT; ++t){
    const bf16* Ac = (t & 1) ? A1 : A0;
    bf16*       An = (t & 1) ? A0 : A1;
    gru_step<<<256, 512, 0, stream>>>(Ac, Wg, WoB, zpn, biasz, bhhn, Wih, cond,
                                      An, bout, out, t);
  }
  // final step t=31: state is in A0 (t=31 odd -> An=A0)
  out_k<<<512, 256, 0, stream>>>(A0, Wout, bout, out, 31);
}